// Round 10
// baseline (653.942 us; speedup 1.0000x reference)
//
#include <hip/hip_runtime.h>
#include <hip/hip_bf16.h>

typedef __bf16 bf16;
typedef __bf16 bf16x4 __attribute__((ext_vector_type(4)));
typedef __bf16 bf16x8 __attribute__((ext_vector_type(8)));
typedef float  f32x4  __attribute__((ext_vector_type(4)));
typedef short  s16x4  __attribute__((ext_vector_type(4)));

#define DEVI __device__ __forceinline__

// B_=2048 windows, N=64 tokens, C=256, H=8 heads, HD=32, NW=64 windows/image
static constexpr float kScale = 0.17677669529663687f;  // 32^-0.5

DEVI f32x4 mfma32(bf16x8 a, bf16x8 b, f32x4 c) {
  return __builtin_amdgcn_mfma_f32_16x16x32_bf16(a, b, c, 0, 0, 0);
}
// K=16 bf16 MFMA; builtin is the "_1k" spelling; host pass falls to inline asm
// (parsed but never emitted: device-only function).
DEVI f32x4 mfma16(bf16x4 a, bf16x4 b, f32x4 c) {
#if __has_builtin(__builtin_amdgcn_mfma_f32_16x16x16bf16_1k)
  return __builtin_amdgcn_mfma_f32_16x16x16bf16_1k(
      __builtin_bit_cast(s16x4, a), __builtin_bit_cast(s16x4, b), c, 0, 0, 0);
#else
  f32x4 d;
  asm volatile("v_mfma_f32_16x16x16_bf16 %0, %1, %2, %3"
               : "=v"(d)
               : "v"(a), "v"(b), "v"(c));
  return d;
#endif
}
DEVI bf16x4 pk4(f32x4 v) {
  bf16x4 p;
  p[0] = (bf16)v[0]; p[1] = (bf16)v[1]; p[2] = (bf16)v[2]; p[3] = (bf16)v[3];
  return p;
}

// Weight fragments in exact per-wave load order:
//   wstream: frag fi = m*8+kq (24 frags), each [wave w][nt][lane][16B] = 16 KB.
//   lane = g*16 + c holds (n = w*64+nt*16+c, k = kq*32+g*8 .. +8).
//   One wf load = 64 lanes x 16B = 1 KB fully-coalesced, L2-resident.
// wpstream: 8 frags (kq), same inner layout.
DEVI const bf16x8* wfp(const char* base, int fi, int w, int nt, int lane) {
  return (const bf16x8*)(base + (((size_t)fi * 16 + w * 4 + nt) * 64 + lane) * 16);
}

// ---------------- prep ----------------
__global__ __launch_bounds__(256) void prep_kernel(
    const float* __restrict__ wq, const float* __restrict__ bq,
    const float* __restrict__ wk, const float* __restrict__ bk,
    const float* __restrict__ wv, const float* __restrict__ bv,
    const float* __restrict__ wp,
    const float* __restrict__ bias_table, const int* __restrict__ rel_index,
    const float* __restrict__ mask,
    char* __restrict__ wstream, char* __restrict__ wpstream,
    float* __restrict__ bqkv, bf16* __restrict__ biasM) {
  int idx = blockIdx.x * 256 + threadIdx.x;
  if (idx < 196608) {                       // 3*256*256 qkv weights
    int m = idx >> 16, n = idx & 255, k = (idx >> 8) & 255;
    const float* w = (m == 0) ? wq : (m == 1 ? wk : wv);
    float v = w[k * 256 + n];
    if (m == 0) v *= kScale;
    int fi = m * 8 + (k >> 5);
    int wv_ = n >> 6, nt = (n >> 4) & 3;
    int lane = ((k >> 3) & 3) * 16 + (n & 15);
    *(bf16*)(wstream + (((size_t)fi * 16 + wv_ * 4 + nt) * 64 + lane) * 16 +
             (k & 7) * 2) = (bf16)v;
  } else if (idx < 262144) {                // + 256*256 proj weight
    int rem = idx - 196608;
    int n = rem & 255, k = (rem >> 8) & 255;
    int fi = k >> 5;
    int wv_ = n >> 6, nt = (n >> 4) & 3;
    int lane = ((k >> 3) & 3) * 16 + (n & 15);
    *(bf16*)(wpstream + (((size_t)fi * 16 + wv_ * 4 + nt) * 64 + lane) * 16 +
             (k & 7) * 2) = (bf16)wp[k * 256 + n];
  } else if (idx < 262912) {                // + 3*256 biases
    int rem = idx - 262144;
    int m = rem >> 8, n = rem & 255;
    const float* b = (m == 0) ? bq : (m == 1 ? bk : bv);
    float v = b[n];
    if (m == 0) v *= kScale;
    bqkv[rem] = v;
  } else if (idx < 2360064) {               // + 64*8*64*64 fused bias+mask (bf16)
    int rem = idx - 262912;
    int w = rem >> 15, h = (rem >> 12) & 7, ij = rem & 4095;
    biasM[rem] = (bf16)(bias_table[rel_index[ij] * 8 + h] + mask[w * 4096 + ij]);
  }
}

// ---------------- fused swin attention block kernel ----------------
// Block = 1 window, 4 waves; wave w owns channel slice [64w,64w+64) = heads
// {2w,2w+1}. HEAD-SEQUENTIAL register diet (R6/R8 spill lesson): per head,
// compute that head's 32-col Q/K/V slice (qp/kp/vp[4][2] = 48 VGPR, not 96),
// run its attention immediately, keep the 16-reg output in registers; write
// obuf only after all xs reads. Peak live ~140 < the (256,3) cap (~170)
// -> 3 blocks/CU. Weights global->reg (L2-hot fragments), no weight LDS,
// 3 barriers total.
__global__ __launch_bounds__(256, 3) void swin_kernel(
    const float* __restrict__ x, const char* __restrict__ wstream,
    const char* __restrict__ wpstream, const float* __restrict__ bqkv,
    const float* __restrict__ bp, const bf16* __restrict__ biasM,
    float* __restrict__ out) {
  __shared__ __align__(16) char xs_ob[32768];  // xs (QKV phase), then obuf

  int tid = threadIdx.x;
  int w = tid >> 6, lane = tid & 63;
  int g = lane >> 4, c = lane & 15;
  int win = blockIdx.x;
  const f32x4 fz = {0.f, 0.f, 0.f, 0.f};

  // ---- stage x window -> bf16 LDS [64 t][256 k], rows 512B, XOR swz ----
  {
    const char* xw = (const char*)(x + (size_t)win * 16384);
#pragma unroll
    for (int i = 0; i < 8; ++i) {
      int gb = i * 8192 + tid * 32;
      float4 f0 = *(const float4*)(xw + gb);
      float4 f1 = *(const float4*)(xw + gb + 16);
      bf16x8 v;
      v[0] = (bf16)f0.x; v[1] = (bf16)f0.y; v[2] = (bf16)f0.z; v[3] = (bf16)f0.w;
      v[4] = (bf16)f1.x; v[5] = (bf16)f1.y; v[6] = (bf16)f1.z; v[7] = (bf16)f1.w;
      int t = gb >> 10, ir = (gb & 1023) >> 1;
      *(bf16x8*)(xs_ob + ((t * 512 + ir) ^ ((t & 7) << 4))) = v;
    }
  }
  __syncthreads();

  bf16x4 ob[2][4][2];  // per-head attention outputs (compile-time indexed)

#pragma unroll
  for (int hh = 0; hh < 2; ++hh) {
    int h = w * 2 + hh;
    bf16x4 qp[4][2], kp[4][2], vp[4][2];

    // ---- QKV for this head's 2 col-tiles (nt = hh*2 + n2), barrier-free ----
#pragma unroll
    for (int m = 0; m < 3; ++m) {
      f32x4 acc[4][2];
      if (m < 2) {
#pragma unroll
        for (int n2 = 0; n2 < 2; ++n2) {
          f32x4 b4 = *(const f32x4*)(bqkv + m * 256 + w * 64 + (hh * 2 + n2) * 16 + g * 4);
#pragma unroll
          for (int tt = 0; tt < 4; ++tt) acc[tt][n2] = b4;
        }
      } else {
#pragma unroll
        for (int n2 = 0; n2 < 2; ++n2) {
          float bv_ = bqkv[512 + w * 64 + (hh * 2 + n2) * 16 + c];
          f32x4 b4 = {bv_, bv_, bv_, bv_};
#pragma unroll
          for (int tt = 0; tt < 4; ++tt) acc[tt][n2] = b4;
        }
      }
#pragma unroll
      for (int kq = 0; kq < 8; ++kq) {
        bf16x8 wf[2], xf[4];
#pragma unroll
        for (int n2 = 0; n2 < 2; ++n2)
          wf[n2] = *wfp(wstream, m * 8 + kq, w, hh * 2 + n2, lane);
#pragma unroll
        for (int tt = 0; tt < 4; ++tt)
          xf[tt] = *(const bf16x8*)(
              xs_ob + (((tt * 16 + c) * 512 + kq * 64 + g * 16) ^ ((c & 7) << 4)));
        if (m < 2) {
#pragma unroll
          for (int tt = 0; tt < 4; ++tt)
#pragma unroll
            for (int n2 = 0; n2 < 2; ++n2)
              acc[tt][n2] = mfma32(wf[n2], xf[tt], acc[tt][n2]);
        } else {
#pragma unroll
          for (int tt = 0; tt < 4; ++tt)
#pragma unroll
            for (int n2 = 0; n2 < 2; ++n2)
              acc[tt][n2] = mfma32(xf[tt], wf[n2], acc[tt][n2]);
        }
      }
#pragma unroll
      for (int tt = 0; tt < 4; ++tt)
#pragma unroll
        for (int n2 = 0; n2 < 2; ++n2) {
          if (m == 0)      qp[tt][n2] = pk4(acc[tt][n2]);
          else if (m == 1) kp[tt][n2] = pk4(acc[tt][n2]);
          else             vp[tt][n2] = pk4(acc[tt][n2]);
        }
    }

    // ---- attention for head h, fully in-register; output held in regs ----
    const bf16* bm = biasM + ((size_t)(win & 63) * 8 + h) * 4096;
#pragma unroll
    for (int mi = 0; mi < 4; ++mi) {
      f32x4 s[4];
#pragma unroll
      for (int mj = 0; mj < 4; ++mj) {
        bf16x4 b4 = *(const bf16x4*)(bm + (mi * 16 + c) * 64 + mj * 16 + g * 4);
        s[mj] = (f32x4){(float)b4[0], (float)b4[1], (float)b4[2], (float)b4[3]};
      }
#pragma unroll
      for (int dd = 0; dd < 2; ++dd)
#pragma unroll
        for (int mj = 0; mj < 4; ++mj)
          s[mj] = mfma16(kp[mj][dd], qp[mi][dd], s[mj]);
      float mx;
      {
        f32x4 m4 = s[0];
#pragma unroll
        for (int mj = 1; mj < 4; ++mj) {
          m4[0] = fmaxf(m4[0], s[mj][0]); m4[1] = fmaxf(m4[1], s[mj][1]);
          m4[2] = fmaxf(m4[2], s[mj][2]); m4[3] = fmaxf(m4[3], s[mj][3]);
        }
        mx = fmaxf(fmaxf(m4[0], m4[1]), fmaxf(m4[2], m4[3]));
        mx = fmaxf(mx, __shfl_xor(mx, 16));
        mx = fmaxf(mx, __shfl_xor(mx, 32));
      }
      float sum;
      {
        f32x4 s4 = fz;
#pragma unroll
        for (int mj = 0; mj < 4; ++mj) {
#pragma unroll
          for (int r = 0; r < 4; ++r) s[mj][r] = __expf(s[mj][r] - mx);
          s4 += s[mj];
        }
        sum = (s4[0] + s4[1]) + (s4[2] + s4[3]);
        sum += __shfl_xor(sum, 16);
        sum += __shfl_xor(sum, 32);
      }
      float rs = 1.0f / sum;
      bf16x4 pf[4];
#pragma unroll
      for (int mj = 0; mj < 4; ++mj) pf[mj] = pk4(s[mj]);
#pragma unroll
      for (int dt = 0; dt < 2; ++dt) {
        f32x4 o = fz;
#pragma unroll
        for (int mj = 0; mj < 4; ++mj)
          o = mfma16(vp[mj][dt], pf[mj], o);
        bf16x4 ov;
        ov[0] = (bf16)(o[0] * rs); ov[1] = (bf16)(o[1] * rs);
        ov[2] = (bf16)(o[2] * rs); ov[3] = (bf16)(o[3] * rs);
        ob[hh][mi][dt] = ov;
      }
    }
  }
  __syncthreads();  // ALL xs reads complete; xs_ob becomes obuf

  // ---- write attention outputs to obuf ----
#pragma unroll
  for (int hh = 0; hh < 2; ++hh) {
    int h = w * 2 + hh;
#pragma unroll
    for (int mi = 0; mi < 4; ++mi)
#pragma unroll
      for (int dt = 0; dt < 2; ++dt)
        *(bf16x4*)(xs_ob + (((mi * 16 + c) * 512 + (h * 32 + dt * 16 + g * 4) * 2) ^
                            ((c & 7) << 4))) = ob[hh][mi][dt];
  }
  __syncthreads();  // obuf visible to all waves

  // ---- projection: 8 frags, barrier-free (qkv state dead -> full acc OK) ----
  f32x4 acc2[4][4];
#pragma unroll
  for (int nt = 0; nt < 4; ++nt) {
    f32x4 b4 = *(const f32x4*)(bp + w * 64 + nt * 16 + g * 4);
#pragma unroll
    for (int tt = 0; tt < 4; ++tt) acc2[tt][nt] = b4;
  }
#pragma unroll
  for (int kq = 0; kq < 8; ++kq) {
    bf16x8 wf[4], of[4];
#pragma unroll
    for (int nt = 0; nt < 4; ++nt) wf[nt] = *wfp(wpstream, kq, w, nt, lane);
#pragma unroll
    for (int tt = 0; tt < 4; ++tt)
      of[tt] = *(const bf16x8*)(
          xs_ob + (((tt * 16 + c) * 512 + kq * 64 + g * 16) ^ ((c & 7) << 4)));
#pragma unroll
    for (int tt = 0; tt < 4; ++tt)
#pragma unroll
      for (int nt = 0; nt < 4; ++nt)
        acc2[tt][nt] = mfma32(wf[nt], of[tt], acc2[tt][nt]);
  }
  // store: C[n][t] -> out[win*64 + t][n], f32x4 along n
#pragma unroll
  for (int tt = 0; tt < 4; ++tt)
#pragma unroll
    for (int nt = 0; nt < 4; ++nt)
      *(f32x4*)(out + ((size_t)win * 64 + tt * 16 + c) * 256 + w * 64 + nt * 16 + g * 4) =
          acc2[tt][nt];
}

extern "C" void kernel_launch(void* const* d_in, const int* in_sizes, int n_in,
                              void* d_out, int out_size, void* d_ws, size_t ws_size,
                              hipStream_t stream) {
  const float* x          = (const float*)d_in[0];
  const float* mask       = (const float*)d_in[1];
  const float* wq         = (const float*)d_in[2];
  const float* bq         = (const float*)d_in[3];
  const float* wk         = (const float*)d_in[4];
  const float* bk         = (const float*)d_in[5];
  const float* wv         = (const float*)d_in[6];
  const float* bv         = (const float*)d_in[7];
  const float* wp         = (const float*)d_in[8];
  const float* bp         = (const float*)d_in[9];
  const float* bias_table = (const float*)d_in[10];
  const int*   rel_index  = (const int*)d_in[11];

  // Workspace (~4.9 MB): wstream | wpstream | bqkv | biasM (bf16)
  char* ws = (char*)d_ws;
  size_t o = 0;
  char* wstream = ws + o;  o += (size_t)24 * 16384;
  char* wpstream = ws + o; o += (size_t)8 * 16384;
  float* bqkv = (float*)(ws + o); o += (size_t)768 * 4;
  bf16* biasM = (bf16*)(ws + o); o += (size_t)64 * 8 * 64 * 64 * 2;
  if (ws_size < o) return;

  prep_kernel<<<9219, 256, 0, stream>>>(wq, bq, wk, bk, wv, bv, wp,
                                        bias_table, rel_index, mask,
                                        wstream, wpstream, bqkv, biasM);
  swin_kernel<<<2048, 256, 0, stream>>>(x, wstream, wpstream, bqkv, bp, biasM,
                                        (float*)d_out);
}

// Round 11
// 155.673 us; speedup vs baseline: 4.2007x; 4.2007x over previous
//
#include <hip/hip_runtime.h>
#include <hip/hip_bf16.h>

typedef __bf16 bf16;
typedef __bf16 bf16x4 __attribute__((ext_vector_type(4)));
typedef __bf16 bf16x8 __attribute__((ext_vector_type(8)));
typedef float  f32x4  __attribute__((ext_vector_type(4)));
typedef short  s16x4  __attribute__((ext_vector_type(4)));

#define DEVI __device__ __forceinline__

// B_=2048 windows, N=64 tokens, C=256, H=8 heads, HD=32, NW=64 windows/image
static constexpr float kScale = 0.17677669529663687f;  // 32^-0.5

DEVI f32x4 mfma32(bf16x8 a, bf16x8 b, f32x4 c) {
  return __builtin_amdgcn_mfma_f32_16x16x32_bf16(a, b, c, 0, 0, 0);
}
// K=16 bf16 MFMA; builtin is the "_1k" spelling; host pass falls to inline asm
// (parsed but never emitted: device-only function).
DEVI f32x4 mfma16(bf16x4 a, bf16x4 b, f32x4 c) {
#if __has_builtin(__builtin_amdgcn_mfma_f32_16x16x16bf16_1k)
  return __builtin_amdgcn_mfma_f32_16x16x16bf16_1k(
      __builtin_bit_cast(s16x4, a), __builtin_bit_cast(s16x4, b), c, 0, 0, 0);
#else
  f32x4 d;
  asm volatile("v_mfma_f32_16x16x16_bf16 %0, %1, %2, %3"
               : "=v"(d)
               : "v"(a), "v"(b), "v"(c));
  return d;
#endif
}
DEVI bf16x4 pk4(f32x4 v) {
  bf16x4 p;
  p[0] = (bf16)v[0]; p[1] = (bf16)v[1]; p[2] = (bf16)v[2]; p[3] = (bf16)v[3];
  return p;
}

// ---------------- prep ----------------
// wsall: 16 chunks of 32 KB. Chunks 0-11 = qkv (m*4 + k/64), 12-15 = wp (k/64).
// Chunk layout [256 n][128 B]: element (n, kk) at n*128 + ((2*kk) ^ ((n&7)<<4))
// (kk = k&63). The XOR bank-swizzle is BAKED into the global layout: the kernel
// copies chunks linearly into LDS and reads with the same XOR (rule #21).
// q-scale folded into m=0. bqkv[m][n] (q-scaled).
// biasM[w64][h][i][j] = bf16(bias_table[rel_index[i][j]][h] + mask[w64][i][j]).
__global__ __launch_bounds__(256) void prep_kernel(
    const float* __restrict__ wq, const float* __restrict__ bq,
    const float* __restrict__ wk, const float* __restrict__ bk,
    const float* __restrict__ wv, const float* __restrict__ bv,
    const float* __restrict__ wp,
    const float* __restrict__ bias_table, const int* __restrict__ rel_index,
    const float* __restrict__ mask,
    char* __restrict__ wsall, float* __restrict__ bqkv, bf16* __restrict__ biasM) {
  int idx = blockIdx.x * 256 + threadIdx.x;
  if (idx < 196608) {                       // 3*256*256 qkv weights
    int m = idx >> 16, n = idx & 255, k = (idx >> 8) & 255;
    const float* w = (m == 0) ? wq : (m == 1 ? wk : wv);
    float v = w[k * 256 + n];
    if (m == 0) v *= kScale;
    *(bf16*)(wsall + (size_t)(m * 4 + (k >> 6)) * 32768 + n * 128 +
             (((k & 63) * 2) ^ ((n & 7) << 4))) = (bf16)v;
  } else if (idx < 262144) {                // + 256*256 proj weight
    int rem = idx - 196608;
    int n = rem & 255, k = (rem >> 8) & 255;
    *(bf16*)(wsall + (size_t)(12 + (k >> 6)) * 32768 + n * 128 +
             (((k & 63) * 2) ^ ((n & 7) << 4))) = (bf16)wp[k * 256 + n];
  } else if (idx < 262912) {                // + 3*256 biases
    int rem = idx - 262144;
    int m = rem >> 8, n = rem & 255;
    const float* b = (m == 0) ? bq : (m == 1 ? bk : bv);
    float v = b[n];
    if (m == 0) v *= kScale;
    bqkv[rem] = v;
  } else if (idx < 2360064) {               // + 64*8*64*64 fused bias+mask (bf16)
    int rem = idx - 262912;
    int w = rem >> 15, h = (rem >> 12) & 7, ij = rem & 4095;
    biasM[rem] = (bf16)(bias_table[rel_index[ij] * 8 + h] + mask[w * 4096 + ij]);
  }
}

// ---------------- fused swin attention block kernel (paired windows) ----------
// Block = 512 threads / 8 waves = TWO windows (waves 0-3 -> win A, 4-7 -> B).
// Wave slice s = w&3 owns channels [64s,64s+64) = heads {2s,2s+1} of its window.
// Weight chunks (32 KB) double-buffered, staged ONCE for both windows; one
// barrier per chunk; per chunk: compute(cur) -> ds_write(nxt, gr loaded last
// iter: vmcnt overlapped by a full iteration of MFMA) -> load gr=i+2 -> sync.
// The chunk pipeline runs through the attention phase (gr holds chunk 13).
// Runtime chunk loop = R4's proven ~128-VGPR codegen (no (.,>=3) bounds: R6/
// R8/R9 all spilled to 84 VGPR / 1.7 GB scratch).
__global__ __launch_bounds__(512, 1) void swin_kernel(
    const float* __restrict__ x, const char* __restrict__ wsall,
    const float* __restrict__ bqkv, const float* __restrict__ bp,
    const bf16* __restrict__ biasM, float* __restrict__ out) {
  __shared__ __align__(16) char xs_ob[65536];  // 2 windows: xs, then obuf
  __shared__ __align__(16) char wbuf[65536];   // 2 x 32 KB weight chunks

  int tid = threadIdx.x;
  int w = tid >> 6, lane = tid & 63;
  int g = lane >> 4, c = lane & 15;
  int hw = w >> 2, s = w & 3;
  int win = blockIdx.x * 2 + hw;
  char* xs = xs_ob + hw * 32768;
  const f32x4 fz = {0.f, 0.f, 0.f, 0.f};

  // ---- stage both windows' x -> bf16 LDS [64 t][256 k], 512B rows, XOR swz ----
  {
    int hw2 = tid >> 8, t256 = tid & 255;
    const char* xw = (const char*)x + ((size_t)blockIdx.x * 2 + hw2) * 65536;
    char* xd = xs_ob + hw2 * 32768;
#pragma unroll
    for (int i = 0; i < 8; ++i) {
      int gb = i * 8192 + t256 * 32;
      float4 f0 = *(const float4*)(xw + gb);
      float4 f1 = *(const float4*)(xw + gb + 16);
      bf16x8 v;
      v[0] = (bf16)f0.x; v[1] = (bf16)f0.y; v[2] = (bf16)f0.z; v[3] = (bf16)f0.w;
      v[4] = (bf16)f1.x; v[5] = (bf16)f1.y; v[6] = (bf16)f1.z; v[7] = (bf16)f1.w;
      int t = gb >> 10, ir = (gb & 1023) >> 1;
      *(bf16x8*)(xd + ((t * 512 + ir) ^ ((t & 7) << 4))) = v;
    }
  }
  // weight pipeline prologue: chunk0 -> buf0, gr = chunk1
  bf16x8 gr[4];
#pragma unroll
  for (int j = 0; j < 4; ++j)
    gr[j] = *(const bf16x8*)(wsall + (size_t)j * 8192 + (size_t)tid * 16);
#pragma unroll
  for (int j = 0; j < 4; ++j)
    *(bf16x8*)(wbuf + j * 8192 + tid * 16) = gr[j];
#pragma unroll
  for (int j = 0; j < 4; ++j)
    gr[j] = *(const bf16x8*)(wsall + 32768 + (size_t)j * 8192 + (size_t)tid * 16);
  __syncthreads();

  bf16x4 qp[4][4], kp[4][4], vp[4][4];
  f32x4 acc[4][4];

  // ---- QKV: 12 chunks (m = i>>2, kc = i&3), ONE barrier each ----
  for (int i = 0; i < 12; ++i) {
    int m = i >> 2, kc = i & 3;
    char* cur = wbuf + (i & 1) * 32768;
    char* nxt = wbuf + ((i + 1) & 1) * 32768;

    if (kc == 0) {
      if (m < 2) {
#pragma unroll
        for (int nt = 0; nt < 4; ++nt) {
          f32x4 b4 = *(const f32x4*)(bqkv + m * 256 + s * 64 + nt * 16 + g * 4);
#pragma unroll
          for (int tt = 0; tt < 4; ++tt) acc[tt][nt] = b4;
        }
      } else {
#pragma unroll
        for (int nt = 0; nt < 4; ++nt) {
          float bv_ = bqkv[512 + s * 64 + nt * 16 + c];
          f32x4 b4 = {bv_, bv_, bv_, bv_};
#pragma unroll
          for (int tt = 0; tt < 4; ++tt) acc[tt][nt] = b4;
        }
      }
    }
#pragma unroll
    for (int kq2 = 0; kq2 < 2; ++kq2) {
      bf16x8 xf[4], wf[4];
#pragma unroll
      for (int tt = 0; tt < 4; ++tt)
        xf[tt] = *(const bf16x8*)(
            xs + (((tt * 16 + c) * 512 + kc * 128 + kq2 * 64 + g * 16) ^ ((c & 7) << 4)));
#pragma unroll
      for (int nt = 0; nt < 4; ++nt)
        wf[nt] = *(const bf16x8*)(
            cur + (s * 64 + nt * 16 + c) * 128 + ((kq2 * 64 + g * 16) ^ ((c & 7) << 4)));
      if (m < 2) {
#pragma unroll
        for (int tt = 0; tt < 4; ++tt)
#pragma unroll
          for (int nt = 0; nt < 4; ++nt)
            acc[tt][nt] = mfma32(wf[nt], xf[tt], acc[tt][nt]);
      } else {
#pragma unroll
        for (int tt = 0; tt < 4; ++tt)
#pragma unroll
          for (int nt = 0; nt < 4; ++nt)
            acc[tt][nt] = mfma32(xf[tt], wf[nt], acc[tt][nt]);
      }
    }
    if (kc == 3) {
#pragma unroll
      for (int tt = 0; tt < 4; ++tt)
#pragma unroll
        for (int nt = 0; nt < 4; ++nt) {
          if (m == 0)      qp[tt][nt] = pk4(acc[tt][nt]);
          else if (m == 1) kp[tt][nt] = pk4(acc[tt][nt]);
          else             vp[tt][nt] = pk4(acc[tt][nt]);
        }
    }
    // stage chunk i+1 (regs loaded a full iteration ago), load chunk i+2
#pragma unroll
    for (int j = 0; j < 4; ++j)
      *(bf16x8*)(nxt + j * 8192 + tid * 16) = gr[j];
    if (i + 2 <= 15) {
#pragma unroll
      for (int j = 0; j < 4; ++j)
        gr[j] = *(const bf16x8*)(wsall + (size_t)(i + 2) * 32768 +
                                 (size_t)j * 8192 + (size_t)tid * 16);
    }
    __syncthreads();
  }
  // after i=11's barrier: all xs reads done (xs becomes obuf); buf0 = proj
  // chunk 12; gr = chunk 13 (held across attention).

  // ---- attention: fully in-register; outputs straight to obuf ----
#pragma unroll
  for (int hh = 0; hh < 2; ++hh) {
    int h = s * 2 + hh;
    const bf16* bm = biasM + ((size_t)(win & 63) * 8 + h) * 4096;
#pragma unroll
    for (int mi = 0; mi < 4; ++mi) {
      f32x4 sv[4];
#pragma unroll
      for (int mj = 0; mj < 4; ++mj) {
        bf16x4 b4 = *(const bf16x4*)(bm + (mi * 16 + c) * 64 + mj * 16 + g * 4);
        sv[mj] = (f32x4){(float)b4[0], (float)b4[1], (float)b4[2], (float)b4[3]};
      }
#pragma unroll
      for (int dd = 0; dd < 2; ++dd)
#pragma unroll
        for (int mj = 0; mj < 4; ++mj)
          sv[mj] = mfma16(kp[mj][hh * 2 + dd], qp[mi][hh * 2 + dd], sv[mj]);
      float mx;
      {
        f32x4 m4 = sv[0];
#pragma unroll
        for (int mj = 1; mj < 4; ++mj) {
          m4[0] = fmaxf(m4[0], sv[mj][0]); m4[1] = fmaxf(m4[1], sv[mj][1]);
          m4[2] = fmaxf(m4[2], sv[mj][2]); m4[3] = fmaxf(m4[3], sv[mj][3]);
        }
        mx = fmaxf(fmaxf(m4[0], m4[1]), fmaxf(m4[2], m4[3]));
        mx = fmaxf(mx, __shfl_xor(mx, 16));
        mx = fmaxf(mx, __shfl_xor(mx, 32));
      }
      float sum;
      {
        f32x4 s4 = fz;
#pragma unroll
        for (int mj = 0; mj < 4; ++mj) {
#pragma unroll
          for (int r = 0; r < 4; ++r) sv[mj][r] = __expf(sv[mj][r] - mx);
          s4 += sv[mj];
        }
        sum = (s4[0] + s4[1]) + (s4[2] + s4[3]);
        sum += __shfl_xor(sum, 16);
        sum += __shfl_xor(sum, 32);
      }
      float rs = 1.0f / sum;
      bf16x4 pf[4];
#pragma unroll
      for (int mj = 0; mj < 4; ++mj) pf[mj] = pk4(sv[mj]);
#pragma unroll
      for (int dt = 0; dt < 2; ++dt) {
        f32x4 o = fz;
#pragma unroll
        for (int mj = 0; mj < 4; ++mj)
          o = mfma16(vp[mj][hh * 2 + dt], pf[mj], o);
        bf16x4 ov;
        ov[0] = (bf16)(o[0] * rs); ov[1] = (bf16)(o[1] * rs);
        ov[2] = (bf16)(o[2] * rs); ov[3] = (bf16)(o[3] * rs);
        *(bf16x4*)(xs + (((mi * 16 + c) * 512 + (h * 32 + dt * 16 + g * 4) * 2) ^
                         ((c & 7) << 4))) = ov;
      }
    }
  }
  __syncthreads();  // obuf visible to all waves of each window

  // ---- projection: chunks 12-15, same single-barrier pipeline ----
  f32x4 acc2[4][4];
#pragma unroll
  for (int nt = 0; nt < 4; ++nt) {
    f32x4 b4 = *(const f32x4*)(bp + s * 64 + nt * 16 + g * 4);
#pragma unroll
    for (int tt = 0; tt < 4; ++tt) acc2[tt][nt] = b4;
  }
  for (int i = 12; i < 16; ++i) {
    int kc = i - 12;
    char* cur = wbuf + (i & 1) * 32768;
    char* nxt = wbuf + ((i + 1) & 1) * 32768;
#pragma unroll
    for (int kq2 = 0; kq2 < 2; ++kq2) {
      bf16x8 of[4], wf[4];
#pragma unroll
      for (int tt = 0; tt < 4; ++tt)
        of[tt] = *(const bf16x8*)(
            xs + (((tt * 16 + c) * 512 + kc * 128 + kq2 * 64 + g * 16) ^ ((c & 7) << 4)));
#pragma unroll
      for (int nt = 0; nt < 4; ++nt)
        wf[nt] = *(const bf16x8*)(
            cur + (s * 64 + nt * 16 + c) * 128 + ((kq2 * 64 + g * 16) ^ ((c & 7) << 4)));
#pragma unroll
      for (int tt = 0; tt < 4; ++tt)
#pragma unroll
        for (int nt = 0; nt < 4; ++nt)
          acc2[tt][nt] = mfma32(wf[nt], of[tt], acc2[tt][nt]);
    }
    if (i < 15) {
#pragma unroll
      for (int j = 0; j < 4; ++j)
        *(bf16x8*)(nxt + j * 8192 + tid * 16) = gr[j];
      if (i + 2 <= 15) {
#pragma unroll
        for (int j = 0; j < 4; ++j)
          gr[j] = *(const bf16x8*)(wsall + (size_t)(i + 2) * 32768 +
                                   (size_t)j * 8192 + (size_t)tid * 16);
      }
      __syncthreads();
    }
  }
  // store: C[n][t] -> out[win*64 + t][n], f32x4 along n
#pragma unroll
  for (int tt = 0; tt < 4; ++tt)
#pragma unroll
    for (int nt = 0; nt < 4; ++nt)
      *(f32x4*)(out + ((size_t)win * 64 + tt * 16 + c) * 256 + s * 64 + nt * 16 + g * 4) =
          acc2[tt][nt];
}

extern "C" void kernel_launch(void* const* d_in, const int* in_sizes, int n_in,
                              void* d_out, int out_size, void* d_ws, size_t ws_size,
                              hipStream_t stream) {
  const float* x          = (const float*)d_in[0];
  const float* mask       = (const float*)d_in[1];
  const float* wq         = (const float*)d_in[2];
  const float* bq         = (const float*)d_in[3];
  const float* wk         = (const float*)d_in[4];
  const float* bk         = (const float*)d_in[5];
  const float* wv         = (const float*)d_in[6];
  const float* bv         = (const float*)d_in[7];
  const float* wp         = (const float*)d_in[8];
  const float* bp         = (const float*)d_in[9];
  const float* bias_table = (const float*)d_in[10];
  const int*   rel_index  = (const int*)d_in[11];

  // Workspace (~4.6 MB): wsall (16 x 32 KB) | bqkv | biasM (bf16)
  char* ws = (char*)d_ws;
  size_t o = 0;
  char* wsall = ws + o; o += (size_t)16 * 32768;
  float* bqkv = (float*)(ws + o); o += (size_t)768 * 4;
  bf16* biasM = (bf16*)(ws + o); o += (size_t)64 * 8 * 64 * 64 * 2;
  if (ws_size < o) return;

  prep_kernel<<<9219, 256, 0, stream>>>(wq, bq, wk, bk, wv, bv, wp,
                                        bias_table, rel_index, mask,
                                        wsall, bqkv, biasM);
  swin_kernel<<<1024, 512, 0, stream>>>(x, wsall, bqkv, bp, biasM, (float*)d_out);
}